// Round 2
// baseline (774.217 us; speedup 1.0000x reference)
//
#include <hip/hip_runtime.h>

constexpr int N      = 100000;
constexpr int E      = 3200000;
constexpr int IN_CH  = 128;
constexpr int HID    = 16;
constexpr int OUT_CH = 64;

constexpr int NPB    = 128;                  // nodes per bucket
constexpr int NB     = (N + NPB - 1) / NPB;  // 782 buckets
constexpr int PBLK   = 256;                  // partition blocks
constexpr int CHUNK  = (E + PBLK - 1) / PBLK;

static_assert(NB == 782, "bucket count");

// ---- pass A: per-block bucket histogram (no global atomics) ----
__global__ __launch_bounds__(256) void k_hist(const int* __restrict__ ei,
                                              unsigned* __restrict__ pbc) {
    __shared__ unsigned cnt[NB];
    int k = blockIdx.x, t = threadIdx.x;
    for (int b = t; b < NB; b += 256) cnt[b] = 0;
    __syncthreads();
    const int* dst = ei + E;
    int e0 = k * CHUNK, e1 = min(e0 + CHUNK, E);
    for (int e = e0 + t; e < e1; e += 256)
        atomicAdd(&cnt[((unsigned)dst[e]) >> 7], 1u);
    __syncthreads();
    for (int b = t; b < NB; b += 256) pbc[(size_t)k * NB + b] = cnt[b];
}

// ---- pass B: column scan: pbc[k][b] -> exclusive prefix over k; tot[b] = column sum ----
__global__ __launch_bounds__(256) void k_scan_cols(unsigned* __restrict__ pbc,
                                                   unsigned* __restrict__ tot) {
    __shared__ unsigned s[PBLK];
    int b = blockIdx.x, t = threadIdx.x;
    unsigned v = pbc[(size_t)t * NB + b];
    s[t] = v;
    __syncthreads();
    for (int off = 1; off < PBLK; off <<= 1) {
        unsigned u = (t >= off) ? s[t - off] : 0u;
        __syncthreads();
        s[t] += u;
        __syncthreads();
    }
    pbc[(size_t)t * NB + b] = s[t] - v;      // exclusive
    if (t == PBLK - 1) tot[b] = s[t];
}

// ---- pass C: scan bucket totals -> bucketBase (exclusive), base[NB] = E ----
__global__ __launch_bounds__(1024) void k_scan_tot(const unsigned* __restrict__ tot,
                                                   unsigned* __restrict__ base) {
    __shared__ unsigned s[1024];
    int t = threadIdx.x;
    unsigned v = (t < NB) ? tot[t] : 0u;
    s[t] = v;
    __syncthreads();
    for (int off = 1; off < 1024; off <<= 1) {
        unsigned u = (t >= off) ? s[t - off] : 0u;
        __syncthreads();
        s[t] += u;
        __syncthreads();
    }
    if (t < NB) base[t] = s[t] - v;
    if (t == 1023) base[NB] = s[t];
}

// ---- pass D: partition edges into buckets (LDS cursors, no global atomics) ----
__global__ __launch_bounds__(256) void k_partition(const int* __restrict__ ei,
                                                   const unsigned* __restrict__ pbc,
                                                   const unsigned* __restrict__ base,
                                                   unsigned* __restrict__ packed) {
    __shared__ unsigned gcur[NB];
    int k = blockIdx.x, t = threadIdx.x;
    for (int b = t; b < NB; b += 256)
        gcur[b] = base[b] + pbc[(size_t)k * NB + b];
    __syncthreads();
    int e0 = k * CHUNK, e1 = min(e0 + CHUNK, E);
    for (int e = e0 + t; e < e1; e += 256) {
        unsigned s = (unsigned)ei[e];
        unsigned d = (unsigned)ei[E + e];
        unsigned b = d >> 7, dl = d & 127u;
        unsigned slot = atomicAdd(&gcur[b], 1u);
        packed[slot] = (dl << 17) | s;
    }
}

// ---- pass E: per-bucket degree count -> dinv = rsqrt(deg+1) ----
__global__ __launch_bounds__(256) void k_deg(const unsigned* __restrict__ packed,
                                             const unsigned* __restrict__ base,
                                             float* __restrict__ dinv) {
    __shared__ unsigned cnt[NPB];
    int b = blockIdx.x, t = threadIdx.x;
    if (t < NPB) cnt[t] = 0;
    __syncthreads();
    unsigned e0 = base[b], e1 = base[b + 1];
    for (unsigned e = e0 + t; e < e1; e += 256)
        atomicAdd(&cnt[packed[e] >> 17], 1u);
    __syncthreads();
    int node = b * NPB + t;
    if (t < NPB && node < N)
        dinv[node] = rsqrtf((float)cnt[t] + 1.0f);
}

// ---- layer1 linear: h1s = dinv * (x @ W1) ----
__global__ __launch_bounds__(256) void k_lin1(const float* __restrict__ x,
                                              const float* __restrict__ W1,
                                              const float* __restrict__ dinv,
                                              float* __restrict__ h1s) {
    __shared__ float W1T[HID][IN_CH + 4];
    __shared__ float xs[16][IN_CH + 4];
    int t = threadIdx.x;
    for (int i = t; i < IN_CH * HID; i += 256) {
        int k = i >> 4, c = i & 15;
        W1T[c][k] = W1[i];
    }
    int rb = blockIdx.x * 16;
    const float* xblk = x + (size_t)rb * IN_CH;
    for (int i = t; i < 16 * IN_CH; i += 256)
        xs[i >> 7][i & 127] = xblk[i];
    __syncthreads();

    int r = t >> 4, c = t & 15;
    int row = rb + r;
    if (row < N) {
        const float4* xr = (const float4*)xs[r];
        const float4* wr = (const float4*)W1T[c];
        float acc = 0.f;
        #pragma unroll
        for (int k4 = 0; k4 < IN_CH / 4; ++k4) {
            float4 a = xr[k4], w = wr[k4];
            acc += a.x * w.x + a.y * w.y + a.z * w.z + a.w * w.w;
        }
        h1s[row * HID + c] = dinv[row] * acc;
    }
}

// ---- layer1 aggregation: h2s[d] = dinv[d]*relu(dinv[d]*(sum h1s[src] + h1s[d]) + b1) ----
__global__ __launch_bounds__(512) void k_agg1(const unsigned* __restrict__ packed,
                                              const unsigned* __restrict__ base,
                                              const float* __restrict__ dinv,
                                              const float* __restrict__ h1s,
                                              const float* __restrict__ b1,
                                              float* __restrict__ h2s) {
    __shared__ float acc[NPB * HID];   // 8 KB
    int b = blockIdx.x, t = threadIdx.x;
    int node0 = b * NPB;
    int nn = min(NPB, N - node0);
    for (int i = t; i < nn * HID; i += 512) acc[i] = h1s[node0 * HID + i]; // self-loop
    __syncthreads();

    unsigned e0 = base[b], e1 = base[b + 1];
    int q = t & 3;         // channel quad
    unsigned eg = e0 + (t >> 2);
    for (unsigned e = eg; e < e1; e += 128) {
        unsigned p = packed[e];
        unsigned src = p & 0x1FFFFu;
        unsigned dl  = p >> 17;
        const float4 v = *(const float4*)(h1s + (size_t)src * HID + q * 4);
        float* a = acc + dl * HID + q * 4;
        atomicAdd(a + 0, v.x);
        atomicAdd(a + 1, v.y);
        atomicAdd(a + 2, v.z);
        atomicAdd(a + 3, v.w);
    }
    __syncthreads();

    for (int i = t; i < nn * HID; i += 512) {
        int node = node0 + (i >> 4);
        int ch = i & 15;
        float di = dinv[node];
        float v = fmaxf(di * acc[i] + b1[ch], 0.f);
        h2s[node0 * HID + i] = di * v;
    }
}

// ---- layer2 aggregation + fused W2/b2: out[d] = (dinv[d]*(sum h2s[src]+h2s[d])) @ W2 + b2 ----
__global__ __launch_bounds__(512) void k_agg2(const unsigned* __restrict__ packed,
                                              const unsigned* __restrict__ base,
                                              const float* __restrict__ dinv,
                                              const float* __restrict__ h2s,
                                              const float* __restrict__ W2,
                                              const float* __restrict__ b2,
                                              float* __restrict__ out) {
    __shared__ float acc[NPB * HID];     // 8 KB
    __shared__ float W2s[HID * OUT_CH];  // 4 KB
    int b = blockIdx.x, t = threadIdx.x;
    int node0 = b * NPB;
    int nn = min(NPB, N - node0);
    for (int i = t; i < HID * OUT_CH; i += 512) W2s[i] = W2[i];
    for (int i = t; i < nn * HID; i += 512) acc[i] = h2s[node0 * HID + i]; // self-loop
    __syncthreads();

    unsigned e0 = base[b], e1 = base[b + 1];
    int q = t & 3;
    unsigned eg = e0 + (t >> 2);
    for (unsigned e = eg; e < e1; e += 128) {
        unsigned p = packed[e];
        unsigned src = p & 0x1FFFFu;
        unsigned dl  = p >> 17;
        const float4 v = *(const float4*)(h2s + (size_t)src * HID + q * 4);
        float* a = acc + dl * HID + q * 4;
        atomicAdd(a + 0, v.x);
        atomicAdd(a + 1, v.y);
        atomicAdd(a + 2, v.z);
        atomicAdd(a + 3, v.w);
    }
    __syncthreads();

    for (int i = t; i < nn * HID; i += 512) acc[i] *= dinv[node0 + (i >> 4)];
    __syncthreads();

    for (int i = t; i < nn * OUT_CH; i += 512) {
        int node = i >> 6, c = i & 63;
        float sum = b2[c];
        const float* ar = acc + node * HID;
        #pragma unroll
        for (int k = 0; k < HID; ++k)
            sum += ar[k] * W2s[k * OUT_CH + c];
        out[(size_t)node0 * OUT_CH + i] = sum;
    }
}

extern "C" void kernel_launch(void* const* d_in, const int* in_sizes, int n_in,
                              void* d_out, int out_size, void* d_ws, size_t ws_size,
                              hipStream_t stream) {
    const float* x  = (const float*)d_in[0];
    const int*   ei = (const int*)d_in[1];
    const float* W1 = (const float*)d_in[2];
    const float* b1 = (const float*)d_in[3];
    const float* W2 = (const float*)d_in[4];
    const float* b2 = (const float*)d_in[5];
    float* out = (float*)d_out;

    char* ws = (char*)d_ws;
    float*    dinv   = (float*)(ws);                    // N floats
    float*    h1s    = (float*)(ws + 400384);           // N*16 floats
    float*    h2s    = (float*)(ws + 6800640);          // N*16 floats
    unsigned* packed = (unsigned*)(ws + 13200896);      // E u32
    unsigned* pbc    = (unsigned*)(ws + 26001152);      // PBLK*NB u32
    unsigned* tot    = (unsigned*)(ws + 26802176);      // NB u32
    unsigned* base   = (unsigned*)(ws + 26805504);      // NB+1 u32

    k_hist      <<<PBLK, 256, 0, stream>>>(ei, pbc);
    k_scan_cols <<<NB, PBLK, 0, stream>>>(pbc, tot);
    k_scan_tot  <<<1, 1024, 0, stream>>>(tot, base);
    k_partition <<<PBLK, 256, 0, stream>>>(ei, pbc, base, packed);
    k_deg       <<<NB, 256, 0, stream>>>(packed, base, dinv);
    k_lin1      <<<(N + 15) / 16, 256, 0, stream>>>(x, W1, dinv, h1s);
    k_agg1      <<<NB, 512, 0, stream>>>(packed, base, dinv, h1s, b1, h2s);
    k_agg2      <<<NB, 512, 0, stream>>>(packed, base, dinv, h2s, W2, b2, out);
}

// Round 3
// 200.486 us; speedup vs baseline: 3.8617x; 3.8617x over previous
//
#include <hip/hip_runtime.h>
#include <hip/hip_fp16.h>

constexpr int N      = 100000;
constexpr int E      = 3200000;
constexpr int IN_CH  = 128;
constexpr int HID    = 16;
constexpr int OUT_CH = 64;

constexpr int NPB    = 128;                  // nodes per bucket
constexpr int NB     = (N + NPB - 1) / NPB;  // 782 buckets
constexpr int PBLK   = 256;                  // partition blocks
constexpr int CHUNK  = (E + PBLK - 1) / PBLK;

// ---- pass A: per-block bucket histogram (no global atomics) ----
__global__ __launch_bounds__(256) void k_hist(const int* __restrict__ ei,
                                              unsigned* __restrict__ pbc) {
    __shared__ unsigned cnt[NB];
    int k = blockIdx.x, t = threadIdx.x;
    for (int b = t; b < NB; b += 256) cnt[b] = 0;
    __syncthreads();
    const int* dst = ei + E;
    int e0 = k * CHUNK, e1 = min(e0 + CHUNK, E);
    for (int e = e0 + t; e < e1; e += 256)
        atomicAdd(&cnt[((unsigned)dst[e]) >> 7], 1u);
    __syncthreads();
    for (int b = t; b < NB; b += 256) pbc[(size_t)k * NB + b] = cnt[b];
}

// ---- pass B: column scan: pbc[k][b] -> exclusive prefix over k; tot[b] = column sum ----
__global__ __launch_bounds__(256) void k_scan_cols(unsigned* __restrict__ pbc,
                                                   unsigned* __restrict__ tot) {
    __shared__ unsigned s[PBLK];
    int b = blockIdx.x, t = threadIdx.x;
    unsigned v = pbc[(size_t)t * NB + b];
    s[t] = v;
    __syncthreads();
    for (int off = 1; off < PBLK; off <<= 1) {
        unsigned u = (t >= off) ? s[t - off] : 0u;
        __syncthreads();
        s[t] += u;
        __syncthreads();
    }
    pbc[(size_t)t * NB + b] = s[t] - v;      // exclusive
    if (t == PBLK - 1) tot[b] = s[t];
}

// ---- pass C: scan bucket totals -> base (exclusive), base[NB] = E ----
__global__ __launch_bounds__(1024) void k_scan_tot(const unsigned* __restrict__ tot,
                                                   unsigned* __restrict__ base) {
    __shared__ unsigned s[1024];
    int t = threadIdx.x;
    unsigned v = (t < NB) ? tot[t] : 0u;
    s[t] = v;
    __syncthreads();
    for (int off = 1; off < 1024; off <<= 1) {
        unsigned u = (t >= off) ? s[t - off] : 0u;
        __syncthreads();
        s[t] += u;
        __syncthreads();
    }
    if (t < NB) base[t] = s[t] - v;
    if (t == 1023) base[NB] = s[t];
}

// ---- pass D: partition edges into buckets (LDS cursors, no global atomics) ----
__global__ __launch_bounds__(256) void k_partition(const int* __restrict__ ei,
                                                   const unsigned* __restrict__ pbc,
                                                   const unsigned* __restrict__ base,
                                                   unsigned* __restrict__ packed) {
    __shared__ unsigned gcur[NB];
    int k = blockIdx.x, t = threadIdx.x;
    for (int b = t; b < NB; b += 256)
        gcur[b] = base[b] + pbc[(size_t)k * NB + b];
    __syncthreads();
    int e0 = k * CHUNK, e1 = min(e0 + CHUNK, E);
    for (int e = e0 + t; e < e1; e += 256) {
        unsigned s = (unsigned)ei[e];
        unsigned d = (unsigned)ei[E + e];
        unsigned b = d >> 7, dl = d & 127u;
        unsigned slot = atomicAdd(&gcur[b], 1u);
        packed[slot] = (dl << 17) | s;       // src<2^17, dl<2^7
    }
}

// ---- pass E: per-bucket counting sort -> sorted_src, node_start, dinv ----
__global__ __launch_bounds__(256) void k_sort(const unsigned* __restrict__ packed,
                                              const unsigned* __restrict__ base,
                                              unsigned* __restrict__ sorted,
                                              unsigned* __restrict__ node_start,
                                              float* __restrict__ dinv) {
    __shared__ unsigned cnt[NPB];
    __shared__ unsigned pref[NPB];
    __shared__ unsigned cur[NPB];
    int b = blockIdx.x, t = threadIdx.x;
    if (t < NPB) cnt[t] = 0;
    __syncthreads();
    unsigned e0 = base[b], e1 = base[b + 1];
    for (unsigned e = e0 + t; e < e1; e += 256)
        atomicAdd(&cnt[packed[e] >> 17], 1u);
    __syncthreads();
    if (t < NPB) pref[t] = cnt[t];
    __syncthreads();
    for (int off = 1; off < NPB; off <<= 1) {
        unsigned u = (t < NPB && t >= off) ? pref[t - off] : 0u;
        __syncthreads();
        if (t < NPB) pref[t] += u;           // inclusive scan
        __syncthreads();
    }
    if (t < NPB) {
        unsigned ex = pref[t] - cnt[t];
        cur[t] = ex;
        int node = b * NPB + t;
        if (node < N) {
            node_start[node] = e0 + ex;
            dinv[node] = rsqrtf((float)cnt[t] + 1.0f);
        }
    }
    if (b == NB - 1 && t == 0) node_start[N] = e1;
    __syncthreads();
    for (unsigned e = e0 + t; e < e1; e += 256) {
        unsigned p = packed[e];
        unsigned slot = e0 + atomicAdd(&cur[p >> 17], 1u);
        sorted[slot] = p & 0x1FFFFu;
    }
}

// ---- layer1 linear: h1s = fp16(dinv * (x @ W1)) ----
__global__ __launch_bounds__(256) void k_lin1(const float* __restrict__ x,
                                              const float* __restrict__ W1,
                                              const float* __restrict__ dinv,
                                              __half* __restrict__ h1s) {
    __shared__ float W1T[HID][IN_CH + 4];
    __shared__ float xs[16][IN_CH + 4];
    int t = threadIdx.x;
    for (int i = t; i < IN_CH * HID; i += 256) {
        int k = i >> 4, c = i & 15;
        W1T[c][k] = W1[i];
    }
    int rb = blockIdx.x * 16;
    const float* xblk = x + (size_t)rb * IN_CH;
    for (int i = t; i < 16 * IN_CH; i += 256)
        xs[i >> 7][i & 127] = xblk[i];
    __syncthreads();

    int r = t >> 4, c = t & 15;
    int row = rb + r;
    if (row < N) {
        const float4* xr = (const float4*)xs[r];
        const float4* wr = (const float4*)W1T[c];
        float acc = 0.f;
        #pragma unroll
        for (int k4 = 0; k4 < IN_CH / 4; ++k4) {
            float4 a = xr[k4], w = wr[k4];
            acc += a.x * w.x + a.y * w.y + a.z * w.z + a.w * w.w;
        }
        h1s[(size_t)row * HID + c] = __float2half_rn(dinv[row] * acc);
    }
}

__device__ __forceinline__ float4 gather16h(const __half* __restrict__ h, unsigned node, int q) {
    float2 raw = *(const float2*)(h + (size_t)node * HID + q * 4);
    const __half2* hp = (const __half2*)&raw;
    float2 lo = __half22float2(hp[0]);
    float2 hi = __half22float2(hp[1]);
    return float4{lo.x, lo.y, hi.x, hi.y};
}

// ---- layer1 aggregation (wave per node): h2s[d] = fp16(dinv*relu(dinv*(sum+self)+b1)) ----
__global__ __launch_bounds__(256) void k_agg1(const unsigned* __restrict__ sorted,
                                              const unsigned* __restrict__ ns,
                                              const float* __restrict__ dinv,
                                              const __half* __restrict__ h1s,
                                              const float* __restrict__ b1,
                                              __half* __restrict__ h2s) {
    int wid = (blockIdx.x * 256 + threadIdx.x) >> 6;   // node, uniform per wave
    int lane = threadIdx.x & 63;
    int q = lane & 3, eslot = lane >> 2;
    unsigned s0 = ns[wid], s1 = ns[wid + 1];
    float4 acc = {0, 0, 0, 0};
    for (unsigned e = s0 + eslot; e < s1; e += 16) {
        float4 v = gather16h(h1s, sorted[e], q);
        acc.x += v.x; acc.y += v.y; acc.z += v.z; acc.w += v.w;
    }
    #pragma unroll
    for (int off = 4; off < 64; off <<= 1) {
        acc.x += __shfl_xor(acc.x, off, 64);
        acc.y += __shfl_xor(acc.y, off, 64);
        acc.z += __shfl_xor(acc.z, off, 64);
        acc.w += __shfl_xor(acc.w, off, 64);
    }
    float4 s = gather16h(h1s, (unsigned)wid, q);       // self-loop
    acc.x += s.x; acc.y += s.y; acc.z += s.z; acc.w += s.w;
    float di = dinv[wid];
    const float4 bb = *(const float4*)(b1 + q * 4);
    if (lane < 4) {
        float2 o01 = {di * fmaxf(di * acc.x + bb.x, 0.f), di * fmaxf(di * acc.y + bb.y, 0.f)};
        float2 o23 = {di * fmaxf(di * acc.z + bb.z, 0.f), di * fmaxf(di * acc.w + bb.w, 0.f)};
        float2 ow;
        ((__half2*)&ow)[0] = __float22half2_rn(o01);
        ((__half2*)&ow)[1] = __float22half2_rn(o23);
        *(float2*)(h2s + (size_t)wid * HID + q * 4) = ow;
    }
}

// ---- layer2 aggregation + fused W2/b2 (wave per node) ----
__global__ __launch_bounds__(256) void k_agg2(const unsigned* __restrict__ sorted,
                                              const unsigned* __restrict__ ns,
                                              const float* __restrict__ dinv,
                                              const __half* __restrict__ h2s,
                                              const float* __restrict__ W2,
                                              const float* __restrict__ b2,
                                              float* __restrict__ out) {
    __shared__ float W2s[HID * OUT_CH];
    int t = threadIdx.x;
    for (int i = t; i < HID * OUT_CH; i += 256) W2s[i] = W2[i];
    __syncthreads();
    int wid = (blockIdx.x * 256 + t) >> 6;
    int lane = t & 63;
    int q = lane & 3, eslot = lane >> 2;
    unsigned s0 = ns[wid], s1 = ns[wid + 1];
    float4 acc = {0, 0, 0, 0};
    for (unsigned e = s0 + eslot; e < s1; e += 16) {
        float4 v = gather16h(h2s, sorted[e], q);
        acc.x += v.x; acc.y += v.y; acc.z += v.z; acc.w += v.w;
    }
    #pragma unroll
    for (int off = 4; off < 64; off <<= 1) {
        acc.x += __shfl_xor(acc.x, off, 64);
        acc.y += __shfl_xor(acc.y, off, 64);
        acc.z += __shfl_xor(acc.z, off, 64);
        acc.w += __shfl_xor(acc.w, off, 64);
    }
    float4 s = gather16h(h2s, (unsigned)wid, q);       // self-loop
    float di = dinv[wid];
    acc.x = di * (acc.x + s.x); acc.y = di * (acc.y + s.y);
    acc.z = di * (acc.z + s.z); acc.w = di * (acc.w + s.w);

    float a[HID];
    #pragma unroll
    for (int qq = 0; qq < 4; ++qq) {
        a[qq * 4 + 0] = __shfl(acc.x, qq, 64);
        a[qq * 4 + 1] = __shfl(acc.y, qq, 64);
        a[qq * 4 + 2] = __shfl(acc.z, qq, 64);
        a[qq * 4 + 3] = __shfl(acc.w, qq, 64);
    }
    int c = lane;
    float sum = b2[c];
    #pragma unroll
    for (int k = 0; k < HID; ++k)
        sum += a[k] * W2s[k * OUT_CH + c];
    out[(size_t)wid * OUT_CH + c] = sum;
}

extern "C" void kernel_launch(void* const* d_in, const int* in_sizes, int n_in,
                              void* d_out, int out_size, void* d_ws, size_t ws_size,
                              hipStream_t stream) {
    const float* x  = (const float*)d_in[0];
    const int*   ei = (const int*)d_in[1];
    const float* W1 = (const float*)d_in[2];
    const float* b1 = (const float*)d_in[3];
    const float* W2 = (const float*)d_in[4];
    const float* b2 = (const float*)d_in[5];
    float* out = (float*)d_out;

    char* ws = (char*)d_ws;
    float*    dinv   = (float*)(ws);                    // N f32            [0, 400000)
    unsigned* node_start = (unsigned*)(ws + 524288);    // (N+1) u32
    unsigned* tot    = (unsigned*)(ws + 1048576);       // NB u32
    unsigned* base   = (unsigned*)(ws + 1056768);       // NB+1 u32
    unsigned* pbc    = (unsigned*)(ws + 1064960);       // PBLK*NB u32 (800768 B)
    unsigned* packed = (unsigned*)(ws + 2097152);       // E u32 (12.8 MB), dead after k_sort
    __half*   h1s    = (__half*)(ws + 2097152);         // N*16 half (3.2 MB) — overlays packed
    __half*   h2s    = (__half*)(ws + 5505024);         // N*16 half (3.2 MB) — overlays packed
    unsigned* sorted = (unsigned*)(ws + 14897152);      // E u32 (12.8 MB), ends at 26.4 MB

    k_hist      <<<PBLK, 256, 0, stream>>>(ei, pbc);
    k_scan_cols <<<NB, PBLK, 0, stream>>>(pbc, tot);
    k_scan_tot  <<<1, 1024, 0, stream>>>(tot, base);
    k_partition <<<PBLK, 256, 0, stream>>>(ei, pbc, base, packed);
    k_sort      <<<NB, 256, 0, stream>>>(packed, base, sorted, node_start, dinv);
    k_lin1      <<<(N + 15) / 16, 256, 0, stream>>>(x, W1, dinv, h1s);
    k_agg1      <<<N / 4, 256, 0, stream>>>(sorted, node_start, dinv, h1s, b1, h2s);
    k_agg2      <<<N / 4, 256, 0, stream>>>(sorted, node_start, dinv, h2s, W2, b2, out);
}